// Round 1
// baseline (9782.144 us; speedup 1.0000x reference)
//
#include <hip/hip_runtime.h>

#define NSTEP 512
#define EDIM  512
#define REC   2048
#define NB    64
#define KSEL  819
#define KC    8       // K chunks of 256 (kc = bid & 7)
#define ZCH   256     // K per block
#define AP    264     // padded k-stride (u16) for LDS tiles
#define CSTR  16896   // 64*AP: component stride inside LDS tiles

typedef unsigned short u16;
typedef __bf16 bf16x8 __attribute__((ext_vector_type(8)));
typedef float  f32x4  __attribute__((ext_vector_type(4)));
typedef unsigned long long ull;

static __device__ __forceinline__ f32x4 mfma16(bf16x8 a, bf16x8 b, f32x4 c) {
    return __builtin_amdgcn_mfma_f32_16x16x32_bf16(a, b, c, 0, 0, 0);
}

// fp32 -> 2 bf16 components (hi, lo): ~17 mantissa bits
static __device__ __forceinline__ void split2(float v, u16& c0, u16& c1) {
    __bf16 b0 = (__bf16)v;
    __bf16 b1 = (__bf16)(v - (float)b0);
    c0 = __builtin_bit_cast(u16, b0);
    c1 = __builtin_bit_cast(u16, b1);
}

// ---- agent-scope (sc1) coherent helpers — compiler-tracked ----
static __device__ __forceinline__ void cstore4f(float* p, float v) {
    __hip_atomic_store((unsigned*)p, __float_as_uint(v), __ATOMIC_RELAXED, __HIP_MEMORY_SCOPE_AGENT);
}
static __device__ __forceinline__ float cload4f(const float* p) {
    return __uint_as_float(__hip_atomic_load((const unsigned*)p, __ATOMIC_RELAXED, __HIP_MEMORY_SCOPE_AGENT));
}
static __device__ __forceinline__ void cstore4u(unsigned* p, unsigned v) {
    __hip_atomic_store(p, v, __ATOMIC_RELAXED, __HIP_MEMORY_SCOPE_AGENT);
}
static __device__ __forceinline__ unsigned cload4u(const unsigned* p) {
    return __hip_atomic_load(p, __ATOMIC_RELAXED, __HIP_MEMORY_SCOPE_AGENT);
}
static __device__ __forceinline__ void cstore8u(void* p, ull v) {
    __hip_atomic_store((ull*)p, v, __ATOMIC_RELAXED, __HIP_MEMORY_SCOPE_AGENT);
}
static __device__ __forceinline__ ull cload8u(const void* p) {
    return __hip_atomic_load((const ull*)p, __ATOMIC_RELAXED, __HIP_MEMORY_SCOPE_AGENT);
}
static __device__ __forceinline__ float2 cload8f(const float* p) {
    ull u = cload8u(p);
    float2 v; __builtin_memcpy(&v, &u, 8);
    return v;
}
static __device__ __forceinline__ void cstore8f(float* p, float a, float b) {
    float2 v; v.x = a; v.y = b;
    ull u; __builtin_memcpy(&u, &v, 8);
    cstore8u(p, u);
}

// ---------------------------------------------------------------------------
// Persistent kernel: 256 blocks x 512 threads.
// Direct-poll barriers (no leader hop):
//   arriveA[bid] = bar[0..255]     all blocks arrive; B blocks poll all 256
//   arriveB[b]   = bar[512+b]      B blocks arrive; everyone polls the 64
// Monotonic gens, >= compares.
// z accumulation: 8 partial planes zpart[kc][64][2048] f32, plain sc1 stores;
// phase B sums the 8 partials (deterministic order). No atomics, no zeroing,
// no ping-pong (writes for t+1 gated behind barB(t) which gates on phase-B
// reads being complete).
// r broadcast: raw tanh f32 (rTf[64][2048]) stored BEFORE the norm reduce +
// one inv[b] scalar after; consumers compute split2(th*inv) during staging
// (bit-identical to previous split2(rn*inv)).
// ---------------------------------------------------------------------------
__global__ __launch_bounds__(512, 1)
void rnn_persistent(const float* __restrict__ x, const float* __restrict__ Wi,
                    const float* __restrict__ Wr, float* __restrict__ out,
                    float* __restrict__ rTf, float* __restrict__ invb,
                    float* __restrict__ zpart, u16* __restrict__ Ybf,
                    unsigned* __restrict__ bar)
{
    extern __shared__ __align__(16) char smem[];
    u16* WrSu = (u16*)smem;                         // + c*CSTR
    u16* aSu  = (u16*)(smem + 67584);               // + c*CSTR
    // Y-precompute views (alias WrS region)
    float* WiP = (float*)smem;                      // [32][128] 16 KB
    float* xP  = (float*)(smem + 16384);            // [32][64]   8 KB
    // phase-B views (alias aS region)
    unsigned*      kS    = (unsigned*)(smem + 67584);            // [2048] 8 KB
    unsigned char* selS  = (unsigned char*)(smem + 67584 + 8192);// 2 KB
    unsigned*      hist  = (unsigned*)(smem + 67584 + 10240);    // [8][256] 8 KB
    __shared__ unsigned s_byte, s_newrem, s_cnteq;
    __shared__ float red[8];
    __shared__ float invS[64];

    const int bid = blockIdx.x;
    const int tid = threadIdx.x;
    const int kc = bid & 7, nc = bid >> 3;
    const int n0 = nc * 64, kcbase = kc * ZCH;
    const int wid = tid >> 6, lane = tid & 63;
    const int q = lane >> 4, l16 = lane & 15;
    const int Moff = (wid & 3) * 16, Npair = wid >> 2;
    const bool isB = (bid < NB);

    // ================= Y precompute: Y[t][b][j] = (x_t @ Wi) bf16 ===========
    {
        const int t0 = bid * 2;
        const int tr4 = (tid >> 5) * 4;
        const int tc4 = (tid & 31) * 4;
        for (int nc2 = 0; nc2 < 16; ++nc2) {
            const int n0y = nc2 * 128;
            f32x4 acc[2][4];
#pragma unroll
            for (int h = 0; h < 2; ++h)
#pragma unroll
                for (int i = 0; i < 4; ++i) acc[h][i] = (f32x4){0,0,0,0};
            for (int kr = 0; kr < 16; ++kr) {
                const int k0y = kr * 32;
                __syncthreads();
                {
                    const int col4 = (tid & 31) * 4, row = tid >> 5;
                    *(float4*)&WiP[row * 128 + col4] =
                        *(const float4*)(Wi + (long long)(k0y + row) * REC + n0y + col4);
                    *(float4*)&WiP[(row + 16) * 128 + col4] =
                        *(const float4*)(Wi + (long long)(k0y + row + 16) * REC + n0y + col4);
                }
                for (int h = 0; h < 2; ++h) {
                    __syncthreads();
                    {
                        const int b = tid & 63, e4 = (tid >> 6) * 4;
                        const float4 v = *(const float4*)(x + ((long long)b * NSTEP + (t0 + h)) * EDIM + k0y + e4);
                        xP[(e4    ) * 64 + b] = v.x;
                        xP[(e4 + 1) * 64 + b] = v.y;
                        xP[(e4 + 2) * 64 + b] = v.z;
                        xP[(e4 + 3) * 64 + b] = v.w;
                    }
                    __syncthreads();
#pragma unroll 8
                    for (int kk = 0; kk < 32; ++kk) {
                        const float4 af = *(const float4*)&xP[kk * 64 + tr4];
                        const float4 bf = *(const float4*)&WiP[kk * 128 + tc4];
                        const float av[4] = {af.x, af.y, af.z, af.w};
#pragma unroll
                        for (int i = 0; i < 4; ++i) {
                            acc[h][i].x += av[i] * bf.x;
                            acc[h][i].y += av[i] * bf.y;
                            acc[h][i].z += av[i] * bf.z;
                            acc[h][i].w += av[i] * bf.w;
                        }
                    }
                }
            }
#pragma unroll
            for (int h = 0; h < 2; ++h)
#pragma unroll
                for (int i = 0; i < 4; ++i) {
                    const long long yrow = (long long)(t0 + h) * 64 + tr4 + i;
                    u16 o[4];
                    o[0] = __builtin_bit_cast(u16, (__bf16)acc[h][i].x);
                    o[1] = __builtin_bit_cast(u16, (__bf16)acc[h][i].y);
                    o[2] = __builtin_bit_cast(u16, (__bf16)acc[h][i].z);
                    o[3] = __builtin_bit_cast(u16, (__bf16)acc[h][i].w);
                    ull pk; __builtin_memcpy(&pk, o, 8);
                    cstore8u(&Ybf[yrow * REC + n0y + tc4], pk);
                }
        }
    }
    // ---- init: zero th state (512 KB) and inv[64] ----
    {
        const int g = bid * 512 + tid;                  // 0..131071 == 64*2048
        cstore4f(rTf + g, 0.f);
        if (bid == 0 && tid < 64) cstore4f(invb + tid, 0.f);
    }
    // init barrier (direct poll, gen 1)
    __syncthreads();
    if (tid == 0) cstore4u(&bar[bid], 1u);
    if (tid < 256) { while (cload4u(&bar[tid]) < 1u) __builtin_amdgcn_s_sleep(1); }
    __asm__ volatile("" ::: "memory");
    __syncthreads();

    // ================= one-time: stage + split Wr tile into LDS =============
    {
        for (int it = 0; it < 32; ++it) {
            const int row = it * 8 + wid;
            const int col = lane;
            const float v = Wr[(long long)(kcbase + row) * REC + n0 + col];
            u16 s0, s1; split2(v, s0, s1);
            const int base = col * AP + row;
            WrSu[base] = s0;
            WrSu[CSTR + base] = s1;
        }
        __syncthreads();
    }

    // ================= main recurrence ======================================
    for (int t = 0; t < NSTEP; ++t) {
        // ---- stage aS: load th f32 + inv, fused scale+split into LDS ----
        {
            if (tid < 64) invS[tid] = cload4f(invb + tid);
            float2 v[16];
#pragma unroll
            for (int i = 0; i < 16; ++i) {
                const int f = i * 512 + tid;            // 8192 float2 tile
                v[i] = cload8f(rTf + (f >> 7) * REC + kcbase + (f & 127) * 2);
            }
            __syncthreads();                            // invS ready
#pragma unroll
            for (int i = 0; i < 16; ++i) {
                const int f = i * 512 + tid;
                const int b = f >> 7, k = (f & 127) * 2;
                const float iv = invS[b];
                u16 x0c0, x0c1, x1c0, x1c1;
                split2(v[i].x * iv, x0c0, x0c1);        // == split2(rn*inv), bit-identical
                split2(v[i].y * iv, x1c0, x1c1);
                *(unsigned*)&aSu[b * AP + k]        = (unsigned)x0c0 | ((unsigned)x1c0 << 16);
                *(unsigned*)&aSu[CSTR + b * AP + k] = (unsigned)x0c1 | ((unsigned)x1c1 << 16);
            }
        }
        __syncthreads();

        // ---- z tile: 3-pass split-bf16 MFMA, K=256 ----
        f32x4 acc0 = {0,0,0,0}, acc1 = {0,0,0,0};
#pragma unroll
        for (int ks = 0; ks < 8; ++ks) {
            const int kk = ks * 32 + q * 8;
            const u16* ap = aSu + (Moff + l16) * AP + kk;
            bf16x8 A0 = *(const bf16x8*)(ap);
            bf16x8 A1 = *(const bf16x8*)(ap + CSTR);
            const u16* bp0 = WrSu + (Npair * 32 + l16) * AP + kk;
            bf16x8 B00 = *(const bf16x8*)(bp0);
            bf16x8 B01 = *(const bf16x8*)(bp0 + CSTR);
            const u16* bp1 = bp0 + 16 * AP;
            bf16x8 B10 = *(const bf16x8*)(bp1);
            bf16x8 B11 = *(const bf16x8*)(bp1 + CSTR);
            acc0 = mfma16(A0, B00, acc0);
            acc1 = mfma16(A0, B10, acc1);
            acc0 = mfma16(A0, B01, acc0);
            acc1 = mfma16(A0, B11, acc1);
            acc0 = mfma16(A1, B00, acc0);
            acc1 = mfma16(A1, B10, acc1);
        }
        // ---- partial z plane: plain sc1 stores (no atomics) ----
        {
            const int colA = n0 + Npair * 32 + l16;
            float* zp = zpart + kc * 131072;
#pragma unroll
            for (int i = 0; i < 4; ++i) {
                float* p = zp + (Moff + q * 4 + i) * REC + colA;
                cstore4f(p,      ((float*)&acc0)[i]);
                cstore4f(p + 16, ((float*)&acc1)[i]);
            }
        }

        // ---- barA: all arrive (syncthreads drains partial stores) ----
        __syncthreads();
        if (tid == 0) cstore4u(&bar[bid], (unsigned)(t + 2));

        // ================= phase B: blocks 0..63, one batch row each ========
        if (isB) {
            const int b = bid;
            const int j0 = tid * 4;
            // issue Y load before the poll (overlaps LLC latency with wait)
            const ushort4 yv = *(const ushort4*)&Ybf[((long long)t * 64 + b) * REC + j0];
            if (tid < 256) {
                while (cload4u(&bar[tid]) < (unsigned)(t + 2)) __builtin_amdgcn_s_sleep(1);
            }
            __asm__ volatile("" ::: "memory");
            __syncthreads();

            // gather z = sum of 8 kc partials (fixed order)
            float zs[4] = {0.f, 0.f, 0.f, 0.f};
#pragma unroll
            for (int c = 0; c < 8; ++c) {
                const float* zp = zpart + c * 131072 + b * REC + j0;
                const float2 u0 = cload8f(zp);
                const float2 u1 = cload8f(zp + 2);
                zs[0] += u0.x; zs[1] += u0.y; zs[2] += u1.x; zs[3] += u1.y;
            }
            unsigned kv[4];
#pragma unroll
            for (int s = 0; s < 4; ++s) {
                const unsigned u = __float_as_uint(zs[s]);
                kv[s] = (u & 0x80000000u) ? ~u : (u | 0x80000000u);
            }
            // ---- radix select w/ early exit, per-wave-private histograms ----
            unsigned* hw_ = hist + wid * 256;
            unsigned prefix = 0, remaining = KSEL;
            int done = 0;
            for (int byte = 3; byte >= 0 && !done; --byte) {
                {
                    uint4 zz = {0u, 0u, 0u, 0u};
                    *(uint4*)&hw_[lane * 4] = zz;
                }
                const int shift = byte * 8;
                const unsigned pmask = (byte == 3) ? 0u : (0xFFFFFFFFu << (shift + 8));
#pragma unroll
                for (int s = 0; s < 4; ++s) {
                    if ((kv[s] & pmask) == prefix)
                        atomicAdd(&hw_[(kv[s] >> shift) & 255u], 1u);
                }
                __syncthreads();
                if (tid < 64) {   // wave 0: combine 8 copies + suffix scan
                    unsigned c0 = 0, c1 = 0, c2 = 0, c3 = 0;
#pragma unroll
                    for (int w = 0; w < 8; ++w) {
                        const uint4 hv = *(const uint4*)&hist[w * 256 + tid * 4];
                        c0 += hv.x; c1 += hv.y; c2 += hv.z; c3 += hv.w;
                    }
                    const unsigned tot = c0 + c1 + c2 + c3;
                    unsigned suf = tot;
#pragma unroll
                    for (int st = 1; st < 64; st <<= 1) {
                        unsigned o = __shfl_down(suf, (unsigned)st);
                        if (tid + st >= 64) o = 0u;
                        suf += o;
                    }
                    unsigned S[5];
                    S[0] = suf; S[1] = suf - c0; S[2] = suf - c0 - c1;
                    S[3] = suf - c0 - c1 - c2; S[4] = suf - tot;
                    const unsigned cc[4] = {c0, c1, c2, c3};
#pragma unroll
                    for (int qq = 0; qq < 4; ++qq) {
                        if (S[qq] >= remaining && S[qq + 1] < remaining) {
                            s_byte = (unsigned)(tid * 4 + qq);
                            s_newrem = remaining - S[qq + 1];
                            s_cnteq = cc[qq];
                        }
                    }
                }
                __syncthreads();
                prefix |= (s_byte << shift);
                remaining = s_newrem;
                if (remaining == s_cnteq) done = 1;  // whole bucket selected
            }
            unsigned char sel[4];
            if (done) {
#pragma unroll
                for (int s = 0; s < 4; ++s)
                    sel[s] = (kv[s] >= prefix) ? 1 : 0;
            } else {
                // tie at exact threshold (step 0: all-zero z). Rare path.
                *(uint4*)&kS[j0] = *(uint4*)kv;
                __syncthreads();
                if (tid == 0) {
                    unsigned rem = remaining;
                    const unsigned T = prefix;
                    for (int j = 0; j < REC; ++j) {
                        const unsigned k = kS[j];
                        unsigned char sl = 0;
                        if (k > T) sl = 1;
                        else if (k == T && rem > 0u) { sl = 1; --rem; }
                        selS[j] = sl;
                    }
                }
                __syncthreads();
#pragma unroll
                for (int s = 0; s < 4; ++s) sel[s] = selS[j0 + s];
            }
            // ---- r_new = tanh(y + masked z); broadcast th BEFORE norm ----
            float th4[4]; float ss = 0.f;
            const u16 ya[4] = {yv.x, yv.y, yv.z, yv.w};
#pragma unroll
            for (int s = 0; s < 4; ++s) {
                const float y = __uint_as_float(((unsigned)ya[s]) << 16);
                const float vv = y + (sel[s] ? zs[s] : 0.f);
                const float th = tanhf(vv);
                th4[s] = th; ss += th * th;
            }
            cstore8f(rTf + b * REC + j0,     th4[0], th4[1]);   // early r store
            cstore8f(rTf + b * REC + j0 + 2, th4[2], th4[3]);
#pragma unroll
            for (int off = 32; off > 0; off >>= 1)
                ss += __shfl_down(ss, (unsigned)off);
            if (lane == 0) red[wid] = ss;
            __syncthreads();
            float a = 0.f;
#pragma unroll
            for (int i = 0; i < 8; ++i) a += red[i];
            const float inv = 1.0f / (sqrtf(a) + 1e-6f);
            if (tid == 0) cstore4f(invb + b, inv);              // 4-byte tail
            if (t == NSTEP - 1) {
                float4 ov;
                ov.x = th4[0] * inv; ov.y = th4[1] * inv;
                ov.z = th4[2] * inv; ov.w = th4[3] * inv;
                *(float4*)&out[(long long)b * REC + j0] = ov;
            }
        }

        // ---- barB: B blocks arrive (r ready); everyone polls the 64 ----
        __syncthreads();
        if (isB && tid == 0) cstore4u(&bar[512 + bid], (unsigned)(t + 1));
        if (tid < 64) {
            while (cload4u(&bar[512 + tid]) < (unsigned)(t + 1)) __builtin_amdgcn_s_sleep(1);
        }
        __asm__ volatile("" ::: "memory");
        __syncthreads();
    }
}

// ---------------------------------------------------------------------------
extern "C" void kernel_launch(void* const* d_in, const int* in_sizes, int n_in,
                              void* d_out, int out_size, void* d_ws, size_t ws_size,
                              hipStream_t stream)
{
    const float* x   = (const float*)d_in[0];   // [64][512][512]
    const float* Win = (const float*)d_in[1];   // [512][2048]
    const float* Wr  = (const float*)d_in[2];   // [2048][2048]
    float* out = (float*)d_out;                 // [64][2048]

    char* ws = (char*)d_ws;
    const size_t BAR = 8192;
    unsigned* bar  = (unsigned*)ws;                          // slots in first 4 KB
    float*    invb = (float*)(ws + 4096);                    // 64 f32 (inside bar page)
    float*    zpart = (float*)(ws + BAR);                    // 8 x 512 KB partial planes
    float*    rTf  = (float*)(ws + BAR + 4194304);           // 512 KB tanh state
    u16*      Ybf  = (u16*)(ws + BAR + 4194304 + 524288);    // 128 MB

    static int smem_set = 0;
    if (!smem_set) {
        hipFuncSetAttribute((const void*)rnn_persistent,
                            hipFuncAttributeMaxDynamicSharedMemorySize, 135168);
        smem_set = 1;
    }
    hipMemsetAsync(bar, 0, BAR, stream);                     // zeroes bar + invb
    rnn_persistent<<<256, 512, 135168, stream>>>(x, Win, Wr, out, rTf, invb, zpart, Ybf, bar);
}